// Round 1
// baseline (1983.138 us; speedup 1.0000x reference)
//
#include <hip/hip_runtime.h>
#include <math.h>

typedef unsigned short u16;
typedef unsigned int u32;
typedef short v8s __attribute__((ext_vector_type(8)));
typedef float v4f __attribute__((ext_vector_type(4)));

#define EMB 300
#define F4 75           // EMB/4
#define KPAD 320
#define NGRP 4096
#define FEAT 256

__device__ __forceinline__ u16 f2bf(float x) {
    u32 u = __float_as_uint(x);
    u += 0x7FFFu + ((u >> 16) & 1u);
    return (u16)(u >> 16);
}

// ------------------- CSR build -------------------
__global__ void k_count(const int* __restrict__ col, int* __restrict__ deg, int E) {
    int e = blockIdx.x * blockDim.x + threadIdx.x;
    if (e < E) atomicAdd(&deg[col[e]], 1);
}

__global__ void k_scan(const int* __restrict__ deg, int* __restrict__ indptr, int N) {
    __shared__ int sums[1024];
    int tid = threadIdx.x;
    int chunk = (N + 1023) >> 10;
    int s0 = tid * chunk, s1 = min(s0 + chunk, N);
    int s = 0;
    for (int i = s0; i < s1; i++) s += deg[i];
    sums[tid] = s;
    __syncthreads();
    for (int off = 1; off < 1024; off <<= 1) {
        int add = (tid >= off) ? sums[tid - off] : 0;
        __syncthreads();
        sums[tid] += add;
        __syncthreads();
    }
    int run = (tid > 0) ? sums[tid - 1] : 0;
    for (int i = s0; i < s1; i++) { run += deg[i]; indptr[i + 1] = run; }
    if (tid == 0) indptr[0] = 0;
}

__global__ void k_fill(const int* __restrict__ row, const int* __restrict__ col,
                       const int* __restrict__ et, const int* __restrict__ ed,
                       const int* __restrict__ indptr, int* __restrict__ cursor,
                       int* __restrict__ packed, int E) {
    int e = blockIdx.x * blockDim.x + threadIdx.x;
    if (e >= E) return;
    int c = col[e];
    int pos = indptr[c] + atomicAdd(&cursor[c], 1);
    packed[pos] = row[e] | ((et[e] * 3 + ed[e]) << 17);
}

// ------------------- h0 init -------------------
__global__ void k_h0(const int* __restrict__ at, const int* __restrict__ ch,
                     const float* __restrict__ e1, const float* __restrict__ e2,
                     float* __restrict__ P, int N) {
    u32 idx = blockIdx.x * blockDim.x + threadIdx.x;
    if (idx >= (u32)N * F4) return;
    u32 n = idx / F4, f = idx % F4;
    float4 a = *(const float4*)(e1 + (size_t)at[n] * EMB + f * 4);
    float4 b = *(const float4*)(e2 + (size_t)ch[n] * EMB + f * 4);
    float4 r;
    r.x = a.x + b.x; r.y = a.y + b.y; r.z = a.z + b.z; r.w = a.w + b.w;
    *(float4*)(P + (size_t)n * EMB + f * 4) = r;
}

// ------------------- W -> bf16 transposed, padded [KPAD x KPAD] -------------------
__global__ void k_wconv(const float* __restrict__ Wl, u16* __restrict__ Wt) {
    int idx = blockIdx.x * blockDim.x + threadIdx.x;
    if (idx >= KPAD * KPAD) return;
    int n = idx / KPAD, k = idx % KPAD;
    float v = (n < EMB && k < EMB) ? Wl[k * EMB + n] : 0.f;
    Wt[idx] = f2bf(v);  // Wt[n*KPAD + k] = W[k][n]
}

// ------------------- identity / BN-finalize scale+shift -------------------
__global__ void k_ident(float* __restrict__ sc, float* __restrict__ sh) {
    int c = threadIdx.x;
    if (c < KPAD) { sc[c] = (c < EMB) ? 1.f : 0.f; sh[c] = 0.f; }
}

__global__ void k_finalize(const float* __restrict__ colsum, const float* __restrict__ colsq,
                           const float* __restrict__ gamma, const float* __restrict__ beta,
                           float* __restrict__ sc, float* __restrict__ sh, int N) {
    int c = threadIdx.x;
    if (c >= KPAD) return;
    if (c < EMB) {
        float inv = 1.f / (float)N;
        float mean = colsum[c] * inv;
        float var = colsq[c] * inv - mean * mean;
        float rstd = rsqrtf(fmaxf(var, 0.f) + 1e-5f);
        float s = gamma[c] * rstd;
        sc[c] = s;
        sh[c] = beta[c] - mean * s;
    } else {
        sc[c] = 0.f; sh[c] = 0.f;
    }
}

// ------------------- GEMM: hx = BNrelu(P) @ W[l]  (bf16 MFMA) -------------------
// A: [M, EMB] fp32 raw; Wt: [KPAD, KPAD] bf16 (Wt[n][k] = W[k][n]); C: [M, EMB] fp32
__global__ __launch_bounds__(256) void k_gemm(
    const float* __restrict__ A, const u16* __restrict__ Wt,
    const float* __restrict__ scale, const float* __restrict__ shift,
    int relu, float* __restrict__ C, int M) {
    __shared__ u16 As[128 * 32];
    __shared__ u16 Bs[64 * 32];
    int m0 = blockIdx.x * 128;
    int n0 = blockIdx.y * 64;
    int tid = threadIdx.x;
    int wave = tid >> 6, lane = tid & 63;
    int lm = lane & 15, quad = lane >> 4;

    v4f acc[2][4] = {};

    for (int kt = 0; kt < KPAD / 32; ++kt) {
        int k0 = kt * 32;
        // stage A: 128 rows x 32 cols, fp32 -> BN+relu -> bf16
#pragma unroll
        for (int i = 0; i < 4; i++) {
            int slot = tid + i * 256;
            int r = slot >> 3, f = slot & 7;
            int m = m0 + r;
            int c = k0 + f * 4;
            float x0 = 0.f, x1 = 0.f, x2 = 0.f, x3 = 0.f;
            if (m < M) {
                const float* ap = A + (size_t)m * EMB;
                if (c + 3 < EMB) {
                    float4 v = *(const float4*)(ap + c);
                    x0 = v.x; x1 = v.y; x2 = v.z; x3 = v.w;
                } else {
                    if (c + 0 < EMB) x0 = ap[c + 0];
                    if (c + 1 < EMB) x1 = ap[c + 1];
                    if (c + 2 < EMB) x2 = ap[c + 2];
                    if (c + 3 < EMB) x3 = ap[c + 3];
                }
            }
            x0 = x0 * scale[c + 0] + shift[c + 0];
            x1 = x1 * scale[c + 1] + shift[c + 1];
            x2 = x2 * scale[c + 2] + shift[c + 2];
            x3 = x3 * scale[c + 3] + shift[c + 3];
            if (relu) {
                x0 = fmaxf(x0, 0.f); x1 = fmaxf(x1, 0.f);
                x2 = fmaxf(x2, 0.f); x3 = fmaxf(x3, 0.f);
            }
            u32 lo = (u32)f2bf(x0) | ((u32)f2bf(x1) << 16);
            u32 hi = (u32)f2bf(x2) | ((u32)f2bf(x3) << 16);
            *(uint2*)&As[r * 32 + f * 4] = make_uint2(lo, hi);
        }
        // stage B: 64 rows (n) x 32 cols (k) from Wt
        {
            int r = tid >> 2, f = tid & 3;
            *(uint4*)&Bs[r * 32 + f * 8] =
                *(const uint4*)(Wt + (size_t)(n0 + r) * KPAD + k0 + f * 8);
        }
        __syncthreads();
        v8s a0 = *(const v8s*)&As[(wave * 32 + lm) * 32 + quad * 8];
        v8s a1 = *(const v8s*)&As[(wave * 32 + 16 + lm) * 32 + quad * 8];
#pragma unroll
        for (int nf = 0; nf < 4; nf++) {
            v8s b = *(const v8s*)&Bs[(nf * 16 + lm) * 32 + quad * 8];
            acc[0][nf] = __builtin_amdgcn_mfma_f32_16x16x32_bf16(a0, b, acc[0][nf], 0, 0, 0);
            acc[1][nf] = __builtin_amdgcn_mfma_f32_16x16x32_bf16(a1, b, acc[1][nf], 0, 0, 0);
        }
        __syncthreads();
    }
#pragma unroll
    for (int mf = 0; mf < 2; mf++)
#pragma unroll
        for (int nf = 0; nf < 4; nf++) {
            int col = n0 + nf * 16 + lm;
            if (col < EMB) {
#pragma unroll
                for (int r = 0; r < 4; r++) {
                    int row = m0 + wave * 32 + mf * 16 + quad * 4 + r;
                    if (row < M) C[(size_t)row * EMB + col] = acc[mf][nf][r];
                }
            }
        }
}

// ------------------- aggregate: out[n] = hx[n] + sum_in hx[src] + S[n] -------------------
__global__ void k_aggregate(const float* __restrict__ hx, const int* __restrict__ indptr,
                            const int* __restrict__ packed, const float* __restrict__ e1,
                            const float* __restrict__ e2, float* __restrict__ out, int N) {
    __shared__ float tab[12];
    if (threadIdx.x < 12) tab[threadIdx.x] = e1[threadIdx.x / 3] + e2[threadIdx.x % 3];
    __syncthreads();
    u32 idx = blockIdx.x * blockDim.x + threadIdx.x;
    if (idx >= (u32)N * F4) return;
    u32 n = idx / F4, f = idx % F4;
    float4 acc = *(const float4*)(hx + (size_t)n * EMB + f * 4);
    float s = e1[4] + e2[0];  // self loop: et=4, ed=0
    int beg = indptr[n], end = indptr[n + 1];
    for (int i = beg; i < end; i++) {
        int v = packed[i];
        int src = v & 0x1FFFF;
        float4 m = *(const float4*)(hx + (size_t)src * EMB + f * 4);
        acc.x += m.x; acc.y += m.y; acc.z += m.z; acc.w += m.w;
        s += tab[v >> 17];
    }
    float4 r;
    r.x = acc.x + s; r.y = acc.y + s; r.z = acc.z + s; r.w = acc.w + s;
    *(float4*)(out + (size_t)n * EMB + f * 4) = r;
}

// ------------------- BN stats -------------------
__global__ void k_stats(const float* __restrict__ out, float* __restrict__ colsum,
                        float* __restrict__ colsq, int N) {
    int c = threadIdx.x;
    int rpb = (N + gridDim.x - 1) / gridDim.x;
    int r0 = blockIdx.x * rpb, r1 = min(r0 + rpb, N);
    if (c >= EMB) return;
    float s = 0.f, q = 0.f;
    for (int r = r0; r < r1; r++) {
        float x = out[(size_t)r * EMB + c];
        s += x; q += x * x;
    }
    atomicAdd(&colsum[c], s);
    atomicAdd(&colsq[c], q);
}

// ------------------- group boundaries from sorted batch -------------------
__global__ void k_bounds(const int* __restrict__ batch, int* __restrict__ gstart, int N) {
    int n = blockIdx.x * blockDim.x + threadIdx.x;
    if (n > N) return;
    int bcur = (n < N) ? batch[n] : NGRP;
    int bprev = (n > 0) ? batch[n - 1] : -1;
    for (int g = bprev + 1; g <= bcur; g++) gstart[g] = n;
}

// ------------------- pool (BN layer4 fused, no relu) -------------------
__global__ void k_pool(const float* __restrict__ out, const float* __restrict__ sc,
                       const float* __restrict__ sh, const int* __restrict__ gstart,
                       float* __restrict__ hg) {
    int g = blockIdx.x;
    int c = threadIdx.x;
    if (c >= EMB) return;
    int r0 = gstart[g], r1 = gstart[g + 1];
    int cnt = r1 - r0;
    float acc = 0.f;
    for (int r = r0; r < r1; r++) acc += out[(size_t)r * EMB + c];
    float res = acc * sc[c] + (float)cnt * sh[c];
    hg[(size_t)g * EMB + c] = res / (float)max(cnt, 1);
}

// ------------------- hf = hg @ feat_W + feat_b -------------------
__global__ __launch_bounds__(256) void k_feat(const float* __restrict__ hg,
                                              const float* __restrict__ fW,
                                              const float* __restrict__ fb,
                                              float* __restrict__ hf) {
    __shared__ float hgs[16 * EMB];
    int g0 = blockIdx.x * 16;
    int tid = threadIdx.x;
    for (int i = tid; i < 16 * EMB; i += 256) {
        int gi = i / EMB, c = i % EMB;
        hgs[i] = hg[(size_t)(g0 + gi) * EMB + c];
    }
    __syncthreads();
    float acc[16];
    float fbv = fb[tid];
#pragma unroll
    for (int gi = 0; gi < 16; gi++) acc[gi] = fbv;
    for (int k = 0; k < EMB; k++) {
        float w = fW[(size_t)k * FEAT + tid];
#pragma unroll
        for (int gi = 0; gi < 16; gi++) acc[gi] += hgs[gi * EMB + k] * w;
    }
#pragma unroll
    for (int gi = 0; gi < 16; gi++) hf[(size_t)(g0 + gi) * FEAT + tid] = acc[gi];
}

// ------------------- head: pred = softplus(hf@W1+b1)@W2+b2 -------------------
__global__ __launch_bounds__(128) void k_head(const float* __restrict__ hf,
                                              const float* __restrict__ W1,
                                              const float* __restrict__ b1,
                                              const float* __restrict__ W2,
                                              const float* __restrict__ b2,
                                              float* __restrict__ pred) {
    __shared__ float hfs[8 * FEAT];
    __shared__ float sred[2][8][2];
    int g0 = blockIdx.x * 8;
    int tid = threadIdx.x;
    for (int i = tid; i < 8 * FEAT; i += 128) {
        int gi = i >> 8, k = i & 255;
        hfs[i] = hf[(size_t)(g0 + gi) * FEAT + k];
    }
    __syncthreads();
    float acc[8];
    float b1v = b1[tid];
#pragma unroll
    for (int gi = 0; gi < 8; gi++) acc[gi] = b1v;
    for (int k = 0; k < FEAT; k++) {
        float w = W1[(size_t)k * 128 + tid];
#pragma unroll
        for (int gi = 0; gi < 8; gi++) acc[gi] += hfs[gi * FEAT + k] * w;
    }
    float w20 = W2[tid * 2], w21 = W2[tid * 2 + 1];
    int wv = tid >> 6;
#pragma unroll
    for (int gi = 0; gi < 8; gi++) {
        float x = acc[gi];
        float t = fmaxf(x, 0.f) + log1pf(expf(-fabsf(x)));
        float p0 = t * w20, p1 = t * w21;
#pragma unroll
        for (int off = 32; off > 0; off >>= 1) {
            p0 += __shfl_down(p0, off);
            p1 += __shfl_down(p1, off);
        }
        if ((tid & 63) == 0) { sred[wv][gi][0] = p0; sred[wv][gi][1] = p1; }
    }
    __syncthreads();
    if (tid < 16) {
        int gi = tid >> 1, o = tid & 1;
        pred[(size_t)(g0 + gi) * 2 + o] = sred[0][gi][o] + sred[1][gi][o] + b2[o];
    }
}

// ------------------- launch -------------------
extern "C" void kernel_launch(void* const* d_in, const int* in_sizes, int n_in,
                              void* d_out, int out_size, void* d_ws, size_t ws_size,
                              hipStream_t stream) {
    const int* atom_type = (const int*)d_in[0];
    const int* chir      = (const int*)d_in[1];
    const int* eidx      = (const int*)d_in[2];
    const int* etype     = (const int*)d_in[3];
    const int* edir      = (const int*)d_in[4];
    const int* batch     = (const int*)d_in[5];
    const float* emb1    = (const float*)d_in[6];
    const float* emb2    = (const float*)d_in[7];
    const float* W       = (const float*)d_in[8];
    const float* ee1     = (const float*)d_in[10];
    const float* ee2     = (const float*)d_in[11];
    const float* gamma   = (const float*)d_in[12];
    const float* beta    = (const float*)d_in[13];
    const float* featW   = (const float*)d_in[14];
    const float* featb   = (const float*)d_in[15];
    const float* hW1     = (const float*)d_in[16];
    const float* hb1     = (const float*)d_in[17];
    const float* hW2     = (const float*)d_in[18];
    const float* hb2     = (const float*)d_in[19];

    int N = in_sizes[0];
    int E = in_sizes[2] / 2;
    const int* erow = eidx;
    const int* ecol = eidx + E;

    size_t off = 0;
    char* base = (char*)d_ws;
    auto carve = [&](size_t bytes) -> void* {
        void* p = base + off;
        off += (bytes + 255) & ~(size_t)255;
        return p;
    };
    float* P        = (float*)carve((size_t)N * EMB * 4);
    float* Q        = (float*)carve((size_t)N * EMB * 4);
    u16*   Wt       = (u16*)  carve((size_t)KPAD * KPAD * 2);
    int*   deg      = (int*)  carve((size_t)N * 4);
    int*   cursor   = (int*)  carve((size_t)N * 4);
    int*   indptr   = (int*)  carve((size_t)(N + 1) * 4);
    int*   packed   = (int*)  carve((size_t)E * 4);
    float* colstats = (float*)carve(2 * KPAD * 4);
    float* colsum = colstats, *colsq = colstats + KPAD;
    float* scale_id = (float*)carve(KPAD * 4);
    float* shift_id = (float*)carve(KPAD * 4);
    float* scale_bn = (float*)carve(KPAD * 4);
    float* shift_bn = (float*)carve(KPAD * 4);
    int*   gstart   = (int*)  carve((size_t)(NGRP + 1) * 4);
    float* hg       = (float*)carve((size_t)NGRP * EMB * 4);

    float* hf   = (float*)d_out;
    float* pred = (float*)d_out + (size_t)NGRP * FEAT;

    hipMemsetAsync(deg, 0, (size_t)N * 4, stream);
    hipMemsetAsync(cursor, 0, (size_t)N * 4, stream);

    int eb = (E + 255) / 256;
    k_count<<<eb, 256, 0, stream>>>(ecol, deg, E);
    k_scan<<<1, 1024, 0, stream>>>(deg, indptr, N);
    k_fill<<<eb, 256, 0, stream>>>(erow, ecol, etype, edir, indptr, cursor, packed, E);

    int nb75 = (N * F4 + 255) / 256;
    k_h0<<<nb75, 256, 0, stream>>>(atom_type, chir, emb1, emb2, P, N);
    k_ident<<<1, KPAD, 0, stream>>>(scale_id, shift_id);

    const float* sc = scale_id;
    const float* sh = shift_id;
    dim3 ggrid((N + 127) / 128, (EMB + 63) / 64);
    for (int l = 0; l < 5; l++) {
        k_wconv<<<(KPAD * KPAD + 255) / 256, 256, 0, stream>>>(W + (size_t)l * EMB * EMB, Wt);
        k_gemm<<<ggrid, 256, 0, stream>>>(P, Wt, sc, sh, l > 0 ? 1 : 0, Q, N);
        k_aggregate<<<nb75, 256, 0, stream>>>(Q, indptr, packed, ee1 + l * 5, ee2 + l * 3, P, N);
        hipMemsetAsync(colstats, 0, 2 * KPAD * 4, stream);
        k_stats<<<512, KPAD, 0, stream>>>(P, colsum, colsq, N);
        k_finalize<<<1, KPAD, 0, stream>>>(colsum, colsq, gamma + l * EMB, beta + l * EMB,
                                           scale_bn, shift_bn, N);
        sc = scale_bn; sh = shift_bn;
    }

    k_bounds<<<(N + 1 + 255) / 256, 256, 0, stream>>>(batch, gstart, N);
    k_pool<<<NGRP, KPAD, 0, stream>>>(P, scale_bn, shift_bn, gstart, hg);
    k_feat<<<NGRP / 16, 256, 0, stream>>>(hg, featW, featb, hf);
    k_head<<<NGRP / 8, 128, 0, stream>>>(hf, hW1, hb1, hW2, hb2, pred);
}

// Round 2
// 1242.431 us; speedup vs baseline: 1.5962x; 1.5962x over previous
//
#include <hip/hip_runtime.h>
#include <math.h>

typedef unsigned short u16;
typedef unsigned int u32;
typedef short v8s __attribute__((ext_vector_type(8)));
typedef float v4f __attribute__((ext_vector_type(4)));

#define EMB 300
#define SP 320            // padded feature stride (bf16 elems)
#define NGRP 4096
#define FEAT 256
#define MT 128
#define NT 160

__device__ __forceinline__ u16 f2bf(float x) {
    u32 u = __float_as_uint(x);
    u += 0x7FFFu + ((u >> 16) & 1u);
    return (u16)(u >> 16);
}
__device__ __forceinline__ float bf2f(u16 h) {
    return __uint_as_float((u32)h << 16);
}
__device__ __forceinline__ void unpack8(uint4 w, float* o) {
    const u32* p = &w.x;
#pragma unroll
    for (int q = 0; q < 4; q++) {
        o[2 * q]     = __uint_as_float(p[q] << 16);
        o[2 * q + 1] = __uint_as_float(p[q] & 0xFFFF0000u);
    }
}

// ------------------- CSR build -------------------
__global__ void k_count(const int* __restrict__ col, int* __restrict__ deg, int E) {
    int e = blockIdx.x * blockDim.x + threadIdx.x;
    if (e < E) atomicAdd(&deg[col[e]], 1);
}

__global__ void k_scan(const int* __restrict__ deg, int* __restrict__ indptr, int N) {
    __shared__ int sums[1024];
    int tid = threadIdx.x;
    int chunk = (N + 1023) >> 10;
    int s0 = tid * chunk, s1 = min(s0 + chunk, N);
    int s = 0;
    for (int i = s0; i < s1; i++) s += deg[i];
    sums[tid] = s;
    __syncthreads();
    for (int off = 1; off < 1024; off <<= 1) {
        int add = (tid >= off) ? sums[tid - off] : 0;
        __syncthreads();
        sums[tid] += add;
        __syncthreads();
    }
    int run = (tid > 0) ? sums[tid - 1] : 0;
    for (int i = s0; i < s1; i++) { run += deg[i]; indptr[i + 1] = run; }
    if (tid == 0) indptr[0] = 0;
}

__global__ void k_fill(const int* __restrict__ row, const int* __restrict__ col,
                       const int* __restrict__ et, const int* __restrict__ ed,
                       const int* __restrict__ indptr, int* __restrict__ cursor,
                       int* __restrict__ packed, int E) {
    int e = blockIdx.x * blockDim.x + threadIdx.x;
    if (e >= E) return;
    int c = col[e];
    int pos = indptr[c] + atomicAdd(&cursor[c], 1);
    packed[pos] = row[e] | ((et[e] * 3 + ed[e]) << 17);
}

// ------------------- h0 init (bf16, padded) -------------------
__global__ void k_h0(const int* __restrict__ at, const int* __restrict__ ch,
                     const float* __restrict__ e1, const float* __restrict__ e2,
                     u16* __restrict__ P, int N) {
    u32 idx = blockIdx.x * blockDim.x + threadIdx.x;
    if (idx >= (u32)N * 40) return;
    u32 n = idx / 40, f = idx % 40;
    int a = at[n], c = ch[n];
    u32 o[4];
#pragma unroll
    for (int q = 0; q < 4; q++) {
        int c0 = f * 8 + q * 2;
        float x0 = 0.f, x1 = 0.f;
        if (c0 < EMB)     x0 = e1[(size_t)a * EMB + c0] + e2[(size_t)c * EMB + c0];
        if (c0 + 1 < EMB) x1 = e1[(size_t)a * EMB + c0 + 1] + e2[(size_t)c * EMB + c0 + 1];
        o[q] = (u32)f2bf(x0) | ((u32)f2bf(x1) << 16);
    }
    *(uint4*)(P + (size_t)n * SP + f * 8) = make_uint4(o[0], o[1], o[2], o[3]);
}

// ------------------- W -> bf16 transposed, padded [SP x SP] -------------------
__global__ void k_wconv(const float* __restrict__ Wl, u16* __restrict__ Wt) {
    int idx = blockIdx.x * blockDim.x + threadIdx.x;
    if (idx >= SP * SP) return;
    int n = idx / SP, k = idx % SP;
    float v = (n < EMB && k < EMB) ? Wl[k * EMB + n] : 0.f;
    Wt[idx] = f2bf(v);  // Wt[n*SP + k] = W[k][n]
}

// ------------------- identity / BN-finalize scale+shift -------------------
__global__ void k_ident(float* __restrict__ sc, float* __restrict__ sh) {
    int c = threadIdx.x;
    if (c < SP) { sc[c] = (c < EMB) ? 1.f : 0.f; sh[c] = 0.f; }
}

__global__ void k_finalize(const float* __restrict__ colsum, const float* __restrict__ colsq,
                           const float* __restrict__ gamma, const float* __restrict__ beta,
                           float* __restrict__ sc, float* __restrict__ sh, int N) {
    int c = threadIdx.x;
    if (c >= SP) return;
    if (c < EMB) {
        float inv = 1.f / (float)N;
        float mean = colsum[c] * inv;
        float var = colsq[c] * inv - mean * mean;
        float rstd = rsqrtf(fmaxf(var, 0.f) + 1e-5f);
        float s = gamma[c] * rstd;
        sc[c] = s;
        sh[c] = beta[c] - mean * s;
    } else {
        sc[c] = 0.f; sh[c] = 0.f;
    }
}

// ------------------- GEMM: Q = BNrelu(P) @ W[l]  (bf16 in/out, full-K blocks) -----
// A: [M, SP] bf16; Wt: [SP, SP] bf16 (Wt[n][k] = W[k][n]); C: [M, SP] bf16
// block tile 128m x 160n, 4 waves 2x2, wave tile 64x80
__global__ __launch_bounds__(256) void k_gemm(
    const u16* __restrict__ A, const u16* __restrict__ Wt,
    const float* __restrict__ scale, const float* __restrict__ shift,
    int relu, u16* __restrict__ C, int M) {
    __shared__ __align__(16) char smem[43008];
    u16* As = (u16*)smem;               // [128][40]
    u16* Bs = (u16*)(smem + 10240);     // [160][40]
    u16* Ct = (u16*)smem;               // [128][168] (overlays staging)

    int m0 = blockIdx.y * MT;
    int n0 = blockIdx.x * NT;
    int tid = threadIdx.x;
    int wave = tid >> 6, lane = tid & 63;
    int wm = wave >> 1, wn = wave & 1;
    int lm = lane & 15, quad = lane >> 4;

    v4f acc[4][5] = {};

    for (int kt = 0; kt < SP / 32; ++kt) {
        int k0 = kt * 32;
        // stage A: 128 rows x 32 cols, bf16 -> BN+relu -> bf16 (512 slots)
#pragma unroll
        for (int i = 0; i < 2; i++) {
            int slot = tid + i * 256;
            int r = slot >> 2, f = slot & 3;
            int m = m0 + r;
            int c = k0 + f * 8;
            uint4 w = make_uint4(0, 0, 0, 0);
            if (m < M) w = *(const uint4*)(A + (size_t)m * SP + c);
            const u32* wp = &w.x;
            u32 o[4];
#pragma unroll
            for (int q = 0; q < 4; q++) {
                float x0 = __uint_as_float(wp[q] << 16);
                float x1 = __uint_as_float(wp[q] & 0xFFFF0000u);
                x0 = x0 * scale[c + q * 2]     + shift[c + q * 2];
                x1 = x1 * scale[c + q * 2 + 1] + shift[c + q * 2 + 1];
                if (relu) { x0 = fmaxf(x0, 0.f); x1 = fmaxf(x1, 0.f); }
                o[q] = (u32)f2bf(x0) | ((u32)f2bf(x1) << 16);
            }
            *(uint4*)(As + r * 40 + f * 8) = make_uint4(o[0], o[1], o[2], o[3]);
        }
        // stage B: 160 rows (n) x 32 cols (k) (640 slots)
        for (int slot = tid; slot < 640; slot += 256) {
            int r = slot >> 2, f = slot & 3;
            *(uint4*)(Bs + r * 40 + f * 8) =
                *(const uint4*)(Wt + (size_t)(n0 + r) * SP + k0 + f * 8);
        }
        __syncthreads();
        v8s a[4];
#pragma unroll
        for (int mf = 0; mf < 4; mf++)
            a[mf] = *(const v8s*)(As + (wm * 64 + mf * 16 + lm) * 40 + quad * 8);
#pragma unroll
        for (int nf = 0; nf < 5; nf++) {
            v8s b = *(const v8s*)(Bs + (wn * 80 + nf * 16 + lm) * 40 + quad * 8);
#pragma unroll
            for (int mf = 0; mf < 4; mf++)
                acc[mf][nf] = __builtin_amdgcn_mfma_f32_16x16x32_bf16(a[mf], b, acc[mf][nf], 0, 0, 0);
        }
        __syncthreads();
    }
    // epilogue: acc -> LDS (bf16) -> coalesced global stores
#pragma unroll
    for (int mf = 0; mf < 4; mf++)
#pragma unroll
        for (int nf = 0; nf < 5; nf++)
#pragma unroll
            for (int r = 0; r < 4; r++) {
                int row = wm * 64 + mf * 16 + quad * 4 + r;
                int col = wn * 80 + nf * 16 + lm;
                Ct[row * 168 + col] = f2bf(acc[mf][nf][r]);
            }
    __syncthreads();
#pragma unroll
    for (int i = 0; i < 10; i++) {
        int slot = tid + i * 256;
        int r = slot / 20, c16 = slot % 20;
        if (m0 + r < M)
            *(uint4*)(C + (size_t)(m0 + r) * SP + n0 + c16 * 8) =
                *(const uint4*)(Ct + r * 168 + c16 * 8);
    }
}

// ------------------- aggregate + fused BN stats -------------------
// P[n] = Q[n] + sum_in Q[src] + S[n];  colstats += column sums/sqsums of P
__global__ __launch_bounds__(320) void k_agg(
    const u16* __restrict__ Q, const int* __restrict__ indptr,
    const int* __restrict__ packed, const float* __restrict__ e1,
    const float* __restrict__ e2, u16* __restrict__ P,
    float* __restrict__ colstats, int N) {
    __shared__ float tab[12];
    __shared__ float part[8][328];
    int tid = threadIdx.x;
    if (tid < 12) tab[tid] = e1[tid / 3] + e2[tid % 3];
    __syncthreads();
    int f = tid % 40;
    int slot = tid / 40;
    int nb = blockIdx.x * 64;
    float sbase = e1[4] + e2[0];   // self loop: et=4, ed=0
    float psum[8] = {0, 0, 0, 0, 0, 0, 0, 0};
    float psq[8]  = {0, 0, 0, 0, 0, 0, 0, 0};

    for (int it = 0; it < 8; it++) {
        int n = nb + it * 8 + slot;
        if (n >= N) continue;
        float acc[8];
        unpack8(*(const uint4*)(Q + (size_t)n * SP + f * 8), acc);
        float s = sbase;
        int beg = indptr[n], end = indptr[n + 1];
        for (int i = beg; i < end; i++) {
            int v = packed[i];
            int src = v & 0x1FFFF;
            float t[8];
            unpack8(*(const uint4*)(Q + (size_t)src * SP + f * 8), t);
#pragma unroll
            for (int j = 0; j < 8; j++) acc[j] += t[j];
            s += tab[v >> 17];
        }
        u32 o[4];
#pragma unroll
        for (int q = 0; q < 4; q++) {
            float r0 = acc[q * 2] + s;
            float r1 = acc[q * 2 + 1] + s;
            psum[q * 2] += r0;       psum[q * 2 + 1] += r1;
            psq[q * 2]  += r0 * r0;  psq[q * 2 + 1]  += r1 * r1;
            o[q] = (u32)f2bf(r0) | ((u32)f2bf(r1) << 16);
        }
        *(uint4*)(P + (size_t)n * SP + f * 8) = make_uint4(o[0], o[1], o[2], o[3]);
    }
    // reduce partials over the 8 node-slots, two rounds (sum then sq)
#pragma unroll
    for (int j = 0; j < 8; j++) part[slot][f * 8 + j] = psum[j];
    __syncthreads();
    {
        float s = 0.f;
#pragma unroll
        for (int k = 0; k < 8; k++) s += part[k][tid];
        atomicAdd(&colstats[tid], s);
    }
    __syncthreads();
#pragma unroll
    for (int j = 0; j < 8; j++) part[slot][f * 8 + j] = psq[j];
    __syncthreads();
    {
        float s = 0.f;
#pragma unroll
        for (int k = 0; k < 8; k++) s += part[k][tid];
        atomicAdd(&colstats[SP + tid], s);
    }
}

// ------------------- group boundaries from sorted batch -------------------
__global__ void k_bounds(const int* __restrict__ batch, int* __restrict__ gstart, int N) {
    int n = blockIdx.x * blockDim.x + threadIdx.x;
    if (n > N) return;
    int bcur = (n < N) ? batch[n] : NGRP;
    int bprev = (n > 0) ? batch[n - 1] : -1;
    for (int g = bprev + 1; g <= bcur; g++) gstart[g] = n;
}

// ------------------- pool (BN layer4 fused, no relu) -------------------
__global__ void k_pool(const u16* __restrict__ P, const float* __restrict__ sc,
                       const float* __restrict__ sh, const int* __restrict__ gstart,
                       float* __restrict__ hg) {
    int g = blockIdx.x;
    int c = threadIdx.x;
    if (c >= EMB) return;
    int r0 = gstart[g], r1 = gstart[g + 1];
    int cnt = r1 - r0;
    float acc = 0.f;
    for (int r = r0; r < r1; r++) acc += bf2f(P[(size_t)r * SP + c]);
    float res = acc * sc[c] + (float)cnt * sh[c];
    hg[(size_t)g * EMB + c] = res / (float)max(cnt, 1);
}

// ------------------- hf = hg @ feat_W + feat_b -------------------
__global__ __launch_bounds__(256) void k_feat(const float* __restrict__ hg,
                                              const float* __restrict__ fW,
                                              const float* __restrict__ fb,
                                              float* __restrict__ hf) {
    __shared__ float hgs[16 * EMB];
    int g0 = blockIdx.x * 16;
    int tid = threadIdx.x;
    for (int i = tid; i < 16 * EMB; i += 256) {
        int gi = i / EMB, c = i % EMB;
        hgs[i] = hg[(size_t)(g0 + gi) * EMB + c];
    }
    __syncthreads();
    float acc[16];
    float fbv = fb[tid];
#pragma unroll
    for (int gi = 0; gi < 16; gi++) acc[gi] = fbv;
    for (int k = 0; k < EMB; k++) {
        float w = fW[(size_t)k * FEAT + tid];
#pragma unroll
        for (int gi = 0; gi < 16; gi++) acc[gi] += hgs[gi * EMB + k] * w;
    }
#pragma unroll
    for (int gi = 0; gi < 16; gi++) hf[(size_t)(g0 + gi) * FEAT + tid] = acc[gi];
}

// ------------------- head: pred = softplus(hf@W1+b1)@W2+b2 -------------------
__global__ __launch_bounds__(128) void k_head(const float* __restrict__ hf,
                                              const float* __restrict__ W1,
                                              const float* __restrict__ b1,
                                              const float* __restrict__ W2,
                                              const float* __restrict__ b2,
                                              float* __restrict__ pred) {
    __shared__ float hfs[8 * FEAT];
    __shared__ float sred[2][8][2];
    int g0 = blockIdx.x * 8;
    int tid = threadIdx.x;
    for (int i = tid; i < 8 * FEAT; i += 128) {
        int gi = i >> 8, k = i & 255;
        hfs[i] = hf[(size_t)(g0 + gi) * FEAT + k];
    }
    __syncthreads();
    float acc[8];
    float b1v = b1[tid];
#pragma unroll
    for (int gi = 0; gi < 8; gi++) acc[gi] = b1v;
    for (int k = 0; k < FEAT; k++) {
        float w = W1[(size_t)k * 128 + tid];
#pragma unroll
        for (int gi = 0; gi < 8; gi++) acc[gi] += hfs[gi * FEAT + k] * w;
    }
    float w20 = W2[tid * 2], w21 = W2[tid * 2 + 1];
    int wv = tid >> 6;
#pragma unroll
    for (int gi = 0; gi < 8; gi++) {
        float x = acc[gi];
        float t = fmaxf(x, 0.f) + log1pf(expf(-fabsf(x)));
        float p0 = t * w20, p1 = t * w21;
#pragma unroll
        for (int off = 32; off > 0; off >>= 1) {
            p0 += __shfl_down(p0, off);
            p1 += __shfl_down(p1, off);
        }
        if ((tid & 63) == 0) { sred[wv][gi][0] = p0; sred[wv][gi][1] = p1; }
    }
    __syncthreads();
    if (tid < 16) {
        int gi = tid >> 1, o = tid & 1;
        pred[(size_t)(g0 + gi) * 2 + o] = sred[0][gi][o] + sred[1][gi][o] + b2[o];
    }
}

// ------------------- launch -------------------
extern "C" void kernel_launch(void* const* d_in, const int* in_sizes, int n_in,
                              void* d_out, int out_size, void* d_ws, size_t ws_size,
                              hipStream_t stream) {
    const int* atom_type = (const int*)d_in[0];
    const int* chir      = (const int*)d_in[1];
    const int* eidx      = (const int*)d_in[2];
    const int* etype     = (const int*)d_in[3];
    const int* edir      = (const int*)d_in[4];
    const int* batch     = (const int*)d_in[5];
    const float* emb1    = (const float*)d_in[6];
    const float* emb2    = (const float*)d_in[7];
    const float* W       = (const float*)d_in[8];
    const float* ee1     = (const float*)d_in[10];
    const float* ee2     = (const float*)d_in[11];
    const float* gamma   = (const float*)d_in[12];
    const float* beta    = (const float*)d_in[13];
    const float* featW   = (const float*)d_in[14];
    const float* featb   = (const float*)d_in[15];
    const float* hW1     = (const float*)d_in[16];
    const float* hb1     = (const float*)d_in[17];
    const float* hW2     = (const float*)d_in[18];
    const float* hb2     = (const float*)d_in[19];

    int N = in_sizes[0];
    int E = in_sizes[2] / 2;
    const int* erow = eidx;
    const int* ecol = eidx + E;

    size_t off = 0;
    char* base = (char*)d_ws;
    auto carve = [&](size_t bytes) -> void* {
        void* p = base + off;
        off += (bytes + 255) & ~(size_t)255;
        return p;
    };
    u16*   P        = (u16*)  carve((size_t)N * SP * 2);
    u16*   Q        = (u16*)  carve((size_t)N * SP * 2);
    u16*   Wt       = (u16*)  carve((size_t)SP * SP * 2);
    int*   deg      = (int*)  carve((size_t)N * 4);
    int*   cursor   = (int*)  carve((size_t)N * 4);
    int*   indptr   = (int*)  carve((size_t)(N + 1) * 4);
    int*   packed   = (int*)  carve((size_t)E * 4);
    float* colstats = (float*)carve(2 * SP * 4);
    float* scale_id = (float*)carve(SP * 4);
    float* shift_id = (float*)carve(SP * 4);
    float* scale_bn = (float*)carve(SP * 4);
    float* shift_bn = (float*)carve(SP * 4);
    int*   gstart   = (int*)  carve((size_t)(NGRP + 1) * 4);
    float* hg       = (float*)carve((size_t)NGRP * EMB * 4);

    float* hf   = (float*)d_out;
    float* pred = (float*)d_out + (size_t)NGRP * FEAT;

    hipMemsetAsync(deg, 0, (size_t)N * 4, stream);
    hipMemsetAsync(cursor, 0, (size_t)N * 4, stream);

    int eb = (E + 255) / 256;
    k_count<<<eb, 256, 0, stream>>>(ecol, deg, E);
    k_scan<<<1, 1024, 0, stream>>>(deg, indptr, N);
    k_fill<<<eb, 256, 0, stream>>>(erow, ecol, etype, edir, indptr, cursor, packed, E);

    int nb40 = (N * 40 + 255) / 256;
    k_h0<<<nb40, 256, 0, stream>>>(atom_type, chir, emb1, emb2, P, N);
    k_ident<<<1, SP, 0, stream>>>(scale_id, shift_id);

    const float* sc = scale_id;
    const float* sh = shift_id;
    dim3 ggrid(2, (N + MT - 1) / MT);   // x = n-tile (fast), y = m-tile
    int ab = (N + 63) / 64;
    for (int l = 0; l < 5; l++) {
        k_wconv<<<(SP * SP + 255) / 256, 256, 0, stream>>>(W + (size_t)l * EMB * EMB, Wt);
        k_gemm<<<ggrid, 256, 0, stream>>>(P, Wt, sc, sh, l > 0 ? 1 : 0, Q, N);
        hipMemsetAsync(colstats, 0, 2 * SP * 4, stream);
        k_agg<<<ab, 320, 0, stream>>>(Q, indptr, packed, ee1 + l * 5, ee2 + l * 3, P,
                                      colstats, N);
        k_finalize<<<1, SP, 0, stream>>>(colstats, colstats + SP, gamma + l * EMB,
                                         beta + l * EMB, scale_bn, shift_bn, N);
        sc = scale_bn; sh = shift_bn;
    }

    k_bounds<<<(N + 1 + 255) / 256, 256, 0, stream>>>(batch, gstart, N);
    k_pool<<<NGRP, SP, 0, stream>>>(P, scale_bn, shift_bn, gstart, hg);
    k_feat<<<NGRP / 16, 256, 0, stream>>>(hg, featW, featb, hf);
    k_head<<<NGRP / 8, 128, 0, stream>>>(hf, hW1, hb1, hW2, hb2, pred);
}

// Round 3
// 1081.251 us; speedup vs baseline: 1.8341x; 1.1491x over previous
//
#include <hip/hip_runtime.h>
#include <math.h>

typedef unsigned short u16;
typedef unsigned int u32;
typedef short v8s __attribute__((ext_vector_type(8)));
typedef float v4f __attribute__((ext_vector_type(4)));

#define EMB 300
#define SP 320            // padded feature stride (bf16 elems)
#define NGRP 4096
#define FEAT 256
#define MT 128
#define NT 160

__device__ __forceinline__ u16 f2bf(float x) {
    u32 u = __float_as_uint(x);
    u += 0x7FFFu + ((u >> 16) & 1u);
    return (u16)(u >> 16);
}
__device__ __forceinline__ float bf2f(u16 h) {
    return __uint_as_float((u32)h << 16);
}
__device__ __forceinline__ void unpack8(uint4 w, float* o) {
    const u32* p = &w.x;
#pragma unroll
    for (int q = 0; q < 4; q++) {
        o[2 * q]     = __uint_as_float(p[q] << 16);
        o[2 * q + 1] = __uint_as_float(p[q] & 0xFFFF0000u);
    }
}

// ------------------- CSR build -------------------
__global__ void k_count(const int* __restrict__ col, int* __restrict__ deg, int E) {
    int e = blockIdx.x * blockDim.x + threadIdx.x;
    if (e < E) atomicAdd(&deg[col[e]], 1);
}

// multi-block scan, phase 1: per-block sums (1024 elems/block)
__global__ __launch_bounds__(256) void k_bsum(const int* __restrict__ deg,
                                              int* __restrict__ bsum, int N) {
    int base = blockIdx.x * 1024 + threadIdx.x * 4;
    int s = 0;
    if (base + 3 < N) {
        int4 v = *(const int4*)(deg + base);
        s = v.x + v.y + v.z + v.w;
    } else {
        for (int j = 0; j < 4; j++) if (base + j < N) s += deg[base + j];
    }
    __shared__ int red[256];
    red[threadIdx.x] = s;
    __syncthreads();
    for (int off = 128; off > 0; off >>= 1) {
        if (threadIdx.x < off) red[threadIdx.x] += red[threadIdx.x + off];
        __syncthreads();
    }
    if (threadIdx.x == 0) bsum[blockIdx.x] = red[0];
}

// phase 2: scan the (<=128) block sums -> exclusive offsets
__global__ __launch_bounds__(128) void k_scanb(const int* __restrict__ bsum,
                                               int* __restrict__ boff, int NB) {
    __shared__ int sh[128];
    int t = threadIdx.x;
    int v = (t < NB) ? bsum[t] : 0;
    sh[t] = v;
    __syncthreads();
    for (int off = 1; off < 128; off <<= 1) {
        int add = (t >= off) ? sh[t - off] : 0;
        __syncthreads();
        sh[t] += add;
        __syncthreads();
    }
    if (t < NB) boff[t] = sh[t] - v;
}

// phase 3: block-local scan + offset -> indptr
__global__ __launch_bounds__(256) void k_indptr(const int* __restrict__ deg,
                                                const int* __restrict__ boff,
                                                int* __restrict__ indptr, int N) {
    int b = blockIdx.x, t = threadIdx.x;
    int base = b * 1024 + t * 4;
    int v[4] = {0, 0, 0, 0};
    if (base + 3 < N) {
        int4 w = *(const int4*)(deg + base);
        v[0] = w.x; v[1] = w.y; v[2] = w.z; v[3] = w.w;
    } else {
        for (int j = 0; j < 4; j++) if (base + j < N) v[j] = deg[base + j];
    }
    int tsum = v[0] + v[1] + v[2] + v[3];
    __shared__ int sh[256];
    sh[t] = tsum;
    __syncthreads();
    for (int off = 1; off < 256; off <<= 1) {
        int add = (t >= off) ? sh[t - off] : 0;
        __syncthreads();
        sh[t] += add;
        __syncthreads();
    }
    int run = boff[b] + sh[t] - tsum;
    for (int j = 0; j < 4; j++) {
        run += v[j];
        if (base + j < N) indptr[base + j + 1] = run;
    }
    if (b == 0 && t == 0) indptr[0] = 0;
}

__global__ void k_fill(const int* __restrict__ row, const int* __restrict__ col,
                       const int* __restrict__ et, const int* __restrict__ ed,
                       const int* __restrict__ indptr, int* __restrict__ cursor,
                       int* __restrict__ packed, int E) {
    int e = blockIdx.x * blockDim.x + threadIdx.x;
    if (e >= E) return;
    int c = col[e];
    int pos = indptr[c] + atomicAdd(&cursor[c], 1);
    packed[pos] = row[e] | ((et[e] * 3 + ed[e]) << 17);
}

// ------------------- h0 init (bf16, padded) -------------------
__global__ void k_h0(const int* __restrict__ at, const int* __restrict__ ch,
                     const float* __restrict__ e1, const float* __restrict__ e2,
                     u16* __restrict__ P, int N) {
    u32 idx = blockIdx.x * blockDim.x + threadIdx.x;
    if (idx >= (u32)N * 40) return;
    u32 n = idx / 40, f = idx % 40;
    int a = at[n], c = ch[n];
    u32 o[4];
#pragma unroll
    for (int q = 0; q < 4; q++) {
        int c0 = f * 8 + q * 2;
        float x0 = 0.f, x1 = 0.f;
        if (c0 < EMB)     x0 = e1[(size_t)a * EMB + c0] + e2[(size_t)c * EMB + c0];
        if (c0 + 1 < EMB) x1 = e1[(size_t)a * EMB + c0 + 1] + e2[(size_t)c * EMB + c0 + 1];
        o[q] = (u32)f2bf(x0) | ((u32)f2bf(x1) << 16);
    }
    *(uint4*)(P + (size_t)n * SP + f * 8) = make_uint4(o[0], o[1], o[2], o[3]);
}

// ------------------- W -> bf16 transposed, padded [SP x SP] -------------------
__global__ void k_wconv(const float* __restrict__ Wl, u16* __restrict__ Wt) {
    int idx = blockIdx.x * blockDim.x + threadIdx.x;
    if (idx >= SP * SP) return;
    int n = idx / SP, k = idx % SP;
    float v = (n < EMB && k < EMB) ? Wl[k * EMB + n] : 0.f;
    Wt[idx] = f2bf(v);  // Wt[n*SP + k] = W[k][n]
}

// ------------------- identity / BN-finalize scale+shift -------------------
__global__ void k_ident(float* __restrict__ sc, float* __restrict__ sh) {
    int c = threadIdx.x;
    if (c < SP) { sc[c] = (c < EMB) ? 1.f : 0.f; sh[c] = 0.f; }
}

__global__ void k_finalize(const float* __restrict__ colsum, const float* __restrict__ colsq,
                           const float* __restrict__ gamma, const float* __restrict__ beta,
                           float* __restrict__ sc, float* __restrict__ sh, int N) {
    int c = threadIdx.x;
    if (c >= SP) return;
    if (c < EMB) {
        float inv = 1.f / (float)N;
        float mean = colsum[c] * inv;
        float var = colsq[c] * inv - mean * mean;
        float rstd = rsqrtf(fmaxf(var, 0.f) + 1e-5f);
        float s = gamma[c] * rstd;
        sc[c] = s;
        sh[c] = beta[c] - mean * s;
    } else {
        sc[c] = 0.f; sh[c] = 0.f;
    }
}

// ------------------- GEMM: Q = BNrelu(P) @ W[l]  (bf16 in/out, full-K blocks) -----
// A: [M, SP] bf16; Wt: [SP, SP] bf16 (Wt[n][k] = W[k][n]); C: [M, SP] bf16
// block tile 128m x 160n, 4 waves 2x2, wave tile 64x80
__global__ __launch_bounds__(256) void k_gemm(
    const u16* __restrict__ A, const u16* __restrict__ Wt,
    const float* __restrict__ scale, const float* __restrict__ shift,
    int relu, u16* __restrict__ C, int M) {
    __shared__ __align__(16) char smem[43008];
    u16* As = (u16*)smem;               // [128][40]
    u16* Bs = (u16*)(smem + 10240);     // [160][40]
    u16* Ct = (u16*)smem;               // [128][168] (overlays staging)

    int m0 = blockIdx.y * MT;
    int n0 = blockIdx.x * NT;
    int tid = threadIdx.x;
    int wave = tid >> 6, lane = tid & 63;
    int wm = wave >> 1, wn = wave & 1;
    int lm = lane & 15, quad = lane >> 4;

    v4f acc[4][5] = {};

    for (int kt = 0; kt < SP / 32; ++kt) {
        int k0 = kt * 32;
        // stage A: 128 rows x 32 cols, bf16 -> BN+relu -> bf16 (512 slots)
#pragma unroll
        for (int i = 0; i < 2; i++) {
            int slot = tid + i * 256;
            int r = slot >> 2, f = slot & 3;
            int m = m0 + r;
            int c = k0 + f * 8;
            uint4 w = make_uint4(0, 0, 0, 0);
            if (m < M) w = *(const uint4*)(A + (size_t)m * SP + c);
            const u32* wp = &w.x;
            u32 o[4];
#pragma unroll
            for (int q = 0; q < 4; q++) {
                float x0 = __uint_as_float(wp[q] << 16);
                float x1 = __uint_as_float(wp[q] & 0xFFFF0000u);
                x0 = x0 * scale[c + q * 2]     + shift[c + q * 2];
                x1 = x1 * scale[c + q * 2 + 1] + shift[c + q * 2 + 1];
                if (relu) { x0 = fmaxf(x0, 0.f); x1 = fmaxf(x1, 0.f); }
                o[q] = (u32)f2bf(x0) | ((u32)f2bf(x1) << 16);
            }
            *(uint4*)(As + r * 40 + f * 8) = make_uint4(o[0], o[1], o[2], o[3]);
        }
        // stage B: 160 rows (n) x 32 cols (k) (640 slots)
        for (int slot = tid; slot < 640; slot += 256) {
            int r = slot >> 2, f = slot & 3;
            *(uint4*)(Bs + r * 40 + f * 8) =
                *(const uint4*)(Wt + (size_t)(n0 + r) * SP + k0 + f * 8);
        }
        __syncthreads();
        v8s a[4];
#pragma unroll
        for (int mf = 0; mf < 4; mf++)
            a[mf] = *(const v8s*)(As + (wm * 64 + mf * 16 + lm) * 40 + quad * 8);
#pragma unroll
        for (int nf = 0; nf < 5; nf++) {
            v8s b = *(const v8s*)(Bs + (wn * 80 + nf * 16 + lm) * 40 + quad * 8);
#pragma unroll
            for (int mf = 0; mf < 4; mf++)
                acc[mf][nf] = __builtin_amdgcn_mfma_f32_16x16x32_bf16(a[mf], b, acc[mf][nf], 0, 0, 0);
        }
        __syncthreads();
    }
    // epilogue: acc -> LDS (bf16) -> coalesced global stores
#pragma unroll
    for (int mf = 0; mf < 4; mf++)
#pragma unroll
        for (int nf = 0; nf < 5; nf++)
#pragma unroll
            for (int r = 0; r < 4; r++) {
                int row = wm * 64 + mf * 16 + quad * 4 + r;
                int col = wn * 80 + nf * 16 + lm;
                Ct[row * 168 + col] = f2bf(acc[mf][nf][r]);
            }
    __syncthreads();
#pragma unroll
    for (int i = 0; i < 10; i++) {
        int slot = tid + i * 256;
        int r = slot / 20, c16 = slot % 20;
        if (m0 + r < M)
            *(uint4*)(C + (size_t)(m0 + r) * SP + n0 + c16 * 8) =
                *(const uint4*)(Ct + r * 168 + c16 * 8);
    }
}

// ------------------- aggregate + fused BN stats -------------------
// P[n] = Q[n] + sum_in Q[src] + S[n];  colstats += column sums/sqsums of P
__global__ __launch_bounds__(320) void k_agg(
    const u16* __restrict__ Q, const int* __restrict__ indptr,
    const int* __restrict__ packed, const float* __restrict__ e1,
    const float* __restrict__ e2, u16* __restrict__ P,
    float* __restrict__ colstats, int N) {
    __shared__ float tab[12];
    __shared__ float part[8][328];
    int tid = threadIdx.x;
    if (tid < 12) tab[tid] = e1[tid / 3] + e2[tid % 3];
    __syncthreads();
    int f = tid % 40;
    int slot = tid / 40;
    int nb = blockIdx.x * 64;
    float sbase = e1[4] + e2[0];   // self loop: et=4, ed=0
    float psum[8] = {0, 0, 0, 0, 0, 0, 0, 0};
    float psq[8]  = {0, 0, 0, 0, 0, 0, 0, 0};

    for (int it = 0; it < 8; it++) {
        int n = nb + it * 8 + slot;
        if (n >= N) continue;
        float acc[8];
        unpack8(*(const uint4*)(Q + (size_t)n * SP + f * 8), acc);
        float s = sbase;
        int beg = indptr[n], end = indptr[n + 1];
        for (int i = beg; i < end; i++) {
            int v = packed[i];
            int src = v & 0x1FFFF;
            float t[8];
            unpack8(*(const uint4*)(Q + (size_t)src * SP + f * 8), t);
#pragma unroll
            for (int j = 0; j < 8; j++) acc[j] += t[j];
            s += tab[v >> 17];
        }
        u32 o[4];
#pragma unroll
        for (int q = 0; q < 4; q++) {
            float r0 = acc[q * 2] + s;
            float r1 = acc[q * 2 + 1] + s;
            psum[q * 2] += r0;       psum[q * 2 + 1] += r1;
            psq[q * 2]  += r0 * r0;  psq[q * 2 + 1]  += r1 * r1;
            o[q] = (u32)f2bf(r0) | ((u32)f2bf(r1) << 16);
        }
        *(uint4*)(P + (size_t)n * SP + f * 8) = make_uint4(o[0], o[1], o[2], o[3]);
    }
    // reduce partials over the 8 node-slots, two rounds (sum then sq)
#pragma unroll
    for (int j = 0; j < 8; j++) part[slot][f * 8 + j] = psum[j];
    __syncthreads();
    {
        float s = 0.f;
#pragma unroll
        for (int k = 0; k < 8; k++) s += part[k][tid];
        atomicAdd(&colstats[tid], s);
    }
    __syncthreads();
#pragma unroll
    for (int j = 0; j < 8; j++) part[slot][f * 8 + j] = psq[j];
    __syncthreads();
    {
        float s = 0.f;
#pragma unroll
        for (int k = 0; k < 8; k++) s += part[k][tid];
        atomicAdd(&colstats[SP + tid], s);
    }
}

// ------------------- group boundaries from sorted batch -------------------
__global__ void k_bounds(const int* __restrict__ batch, int* __restrict__ gstart, int N) {
    int n = blockIdx.x * blockDim.x + threadIdx.x;
    if (n > N) return;
    int bcur = (n < N) ? batch[n] : NGRP;
    int bprev = (n > 0) ? batch[n - 1] : -1;
    for (int g = bprev + 1; g <= bcur; g++) gstart[g] = n;
}

// ------------------- pool (BN layer4 fused, no relu) -------------------
__global__ void k_pool(const u16* __restrict__ P, const float* __restrict__ sc,
                       const float* __restrict__ sh, const int* __restrict__ gstart,
                       float* __restrict__ hg) {
    int g = blockIdx.x;
    int c = threadIdx.x;
    if (c >= EMB) return;
    int r0 = gstart[g], r1 = gstart[g + 1];
    int cnt = r1 - r0;
    float acc = 0.f;
    for (int r = r0; r < r1; r++) acc += bf2f(P[(size_t)r * SP + c]);
    float res = acc * sc[c] + (float)cnt * sh[c];
    hg[(size_t)g * EMB + c] = res / (float)max(cnt, 1);
}

// ------------------- hf = hg @ feat_W + feat_b -------------------
__global__ __launch_bounds__(256) void k_feat(const float* __restrict__ hg,
                                              const float* __restrict__ fW,
                                              const float* __restrict__ fb,
                                              float* __restrict__ hf) {
    __shared__ float hgs[16 * EMB];
    int g0 = blockIdx.x * 16;
    int tid = threadIdx.x;
    for (int i = tid; i < 16 * EMB; i += 256) {
        int gi = i / EMB, c = i % EMB;
        hgs[i] = hg[(size_t)(g0 + gi) * EMB + c];
    }
    __syncthreads();
    float acc[16];
    float fbv = fb[tid];
#pragma unroll
    for (int gi = 0; gi < 16; gi++) acc[gi] = fbv;
    for (int k = 0; k < EMB; k++) {
        float w = fW[(size_t)k * FEAT + tid];
#pragma unroll
        for (int gi = 0; gi < 16; gi++) acc[gi] += hgs[gi * EMB + k] * w;
    }
#pragma unroll
    for (int gi = 0; gi < 16; gi++) hf[(size_t)(g0 + gi) * FEAT + tid] = acc[gi];
}

// ------------------- head: pred = softplus(hf@W1+b1)@W2+b2 -------------------
__global__ __launch_bounds__(128) void k_head(const float* __restrict__ hf,
                                              const float* __restrict__ W1,
                                              const float* __restrict__ b1,
                                              const float* __restrict__ W2,
                                              const float* __restrict__ b2,
                                              float* __restrict__ pred) {
    __shared__ float hfs[8 * FEAT];
    __shared__ float sred[2][8][2];
    int g0 = blockIdx.x * 8;
    int tid = threadIdx.x;
    for (int i = tid; i < 8 * FEAT; i += 128) {
        int gi = i >> 8, k = i & 255;
        hfs[i] = hf[(size_t)(g0 + gi) * FEAT + k];
    }
    __syncthreads();
    float acc[8];
    float b1v = b1[tid];
#pragma unroll
    for (int gi = 0; gi < 8; gi++) acc[gi] = b1v;
    for (int k = 0; k < FEAT; k++) {
        float w = W1[(size_t)k * 128 + tid];
#pragma unroll
        for (int gi = 0; gi < 8; gi++) acc[gi] += hfs[gi * FEAT + k] * w;
    }
    float w20 = W2[tid * 2], w21 = W2[tid * 2 + 1];
    int wv = tid >> 6;
#pragma unroll
    for (int gi = 0; gi < 8; gi++) {
        float x = acc[gi];
        float t = fmaxf(x, 0.f) + log1pf(expf(-fabsf(x)));
        float p0 = t * w20, p1 = t * w21;
#pragma unroll
        for (int off = 32; off > 0; off >>= 1) {
            p0 += __shfl_down(p0, off);
            p1 += __shfl_down(p1, off);
        }
        if ((tid & 63) == 0) { sred[wv][gi][0] = p0; sred[wv][gi][1] = p1; }
    }
    __syncthreads();
    if (tid < 16) {
        int gi = tid >> 1, o = tid & 1;
        pred[(size_t)(g0 + gi) * 2 + o] = sred[0][gi][o] + sred[1][gi][o] + b2[o];
    }
}

// ------------------- launch -------------------
extern "C" void kernel_launch(void* const* d_in, const int* in_sizes, int n_in,
                              void* d_out, int out_size, void* d_ws, size_t ws_size,
                              hipStream_t stream) {
    const int* atom_type = (const int*)d_in[0];
    const int* chir      = (const int*)d_in[1];
    const int* eidx      = (const int*)d_in[2];
    const int* etype     = (const int*)d_in[3];
    const int* edir      = (const int*)d_in[4];
    const int* batch     = (const int*)d_in[5];
    const float* emb1    = (const float*)d_in[6];
    const float* emb2    = (const float*)d_in[7];
    const float* W       = (const float*)d_in[8];
    const float* ee1     = (const float*)d_in[10];
    const float* ee2     = (const float*)d_in[11];
    const float* gamma   = (const float*)d_in[12];
    const float* beta    = (const float*)d_in[13];
    const float* featW   = (const float*)d_in[14];
    const float* featb   = (const float*)d_in[15];
    const float* hW1     = (const float*)d_in[16];
    const float* hb1     = (const float*)d_in[17];
    const float* hW2     = (const float*)d_in[18];
    const float* hb2     = (const float*)d_in[19];

    int N = in_sizes[0];
    int E = in_sizes[2] / 2;
    const int* erow = eidx;
    const int* ecol = eidx + E;

    size_t off = 0;
    char* base = (char*)d_ws;
    auto carve = [&](size_t bytes) -> void* {
        void* p = base + off;
        off += (bytes + 255) & ~(size_t)255;
        return p;
    };
    u16*   P        = (u16*)  carve((size_t)N * SP * 2);
    u16*   Q        = (u16*)  carve((size_t)N * SP * 2);
    u16*   Wt       = (u16*)  carve((size_t)SP * SP * 2);
    int*   deg      = (int*)  carve((size_t)N * 4);
    int*   cursor   = (int*)  carve((size_t)N * 4);
    int*   indptr   = (int*)  carve((size_t)(N + 1) * 4);
    int*   packed   = (int*)  carve((size_t)E * 4);
    int*   bsum     = (int*)  carve(1024 * 4);
    int*   boff     = (int*)  carve(1024 * 4);
    float* colstats = (float*)carve(2 * SP * 4);
    float* scale_id = (float*)carve(SP * 4);
    float* shift_id = (float*)carve(SP * 4);
    float* scale_bn = (float*)carve(SP * 4);
    float* shift_bn = (float*)carve(SP * 4);
    int*   gstart   = (int*)  carve((size_t)(NGRP + 1) * 4);
    float* hg       = (float*)carve((size_t)NGRP * EMB * 4);

    float* hf   = (float*)d_out;
    float* pred = (float*)d_out + (size_t)NGRP * FEAT;

    hipMemsetAsync(deg, 0, (size_t)N * 4, stream);
    hipMemsetAsync(cursor, 0, (size_t)N * 4, stream);

    int eb = (E + 255) / 256;
    int NB = (N + 1023) / 1024;
    k_count<<<eb, 256, 0, stream>>>(ecol, deg, E);
    k_bsum<<<NB, 256, 0, stream>>>(deg, bsum, N);
    k_scanb<<<1, 128, 0, stream>>>(bsum, boff, NB);
    k_indptr<<<NB, 256, 0, stream>>>(deg, boff, indptr, N);
    k_fill<<<eb, 256, 0, stream>>>(erow, ecol, etype, edir, indptr, cursor, packed, E);

    int nb40 = (N * 40 + 255) / 256;
    k_h0<<<nb40, 256, 0, stream>>>(atom_type, chir, emb1, emb2, P, N);
    k_ident<<<1, SP, 0, stream>>>(scale_id, shift_id);

    const float* sc = scale_id;
    const float* sh = shift_id;
    dim3 ggrid(2, (N + MT - 1) / MT);   // x = n-tile (fast), y = m-tile
    int ab = (N + 63) / 64;
    for (int l = 0; l < 5; l++) {
        k_wconv<<<(SP * SP + 255) / 256, 256, 0, stream>>>(W + (size_t)l * EMB * EMB, Wt);
        k_gemm<<<ggrid, 256, 0, stream>>>(P, Wt, sc, sh, l > 0 ? 1 : 0, Q, N);
        hipMemsetAsync(colstats, 0, 2 * SP * 4, stream);
        k_agg<<<ab, 320, 0, stream>>>(Q, indptr, packed, ee1 + l * 5, ee2 + l * 3, P,
                                      colstats, N);
        k_finalize<<<1, SP, 0, stream>>>(colstats, colstats + SP, gamma + l * EMB,
                                         beta + l * EMB, scale_bn, shift_bn, N);
        sc = scale_bn; sh = shift_bn;
    }

    k_bounds<<<(N + 1 + 255) / 256, 256, 0, stream>>>(batch, gstart, N);
    k_pool<<<NGRP, SP, 0, stream>>>(P, scale_bn, shift_bn, gstart, hg);
    k_feat<<<NGRP / 16, 256, 0, stream>>>(hg, featW, featb, hf);
    k_head<<<NGRP / 8, 128, 0, stream>>>(hf, hW1, hb1, hW2, hb2, pred);
}

// Round 4
// 977.828 us; speedup vs baseline: 2.0281x; 1.1058x over previous
//
#include <hip/hip_runtime.h>
#include <math.h>

typedef unsigned short u16;
typedef unsigned int u32;
typedef short v8s __attribute__((ext_vector_type(8)));
typedef float v4f __attribute__((ext_vector_type(4)));

#define EMB 300
#define SP 320            // padded feature stride (bf16 elems)
#define NGRP 4096
#define FEAT 256
#define MT 128
#define NT 160
#define NCOMB 357         // 119 atom types x 3 chirality

__device__ __forceinline__ u16 f2bf(float x) {
    u32 u = __float_as_uint(x);
    u += 0x7FFFu + ((u >> 16) & 1u);
    return (u16)(u >> 16);
}
__device__ __forceinline__ float bf2f(u16 h) {
    return __uint_as_float((u32)h << 16);
}
__device__ __forceinline__ void unpack8(uint4 w, float* o) {
    const u32* p = &w.x;
#pragma unroll
    for (int q = 0; q < 4; q++) {
        o[2 * q]     = __uint_as_float(p[q] << 16);
        o[2 * q + 1] = __uint_as_float(p[q] & 0xFFFF0000u);
    }
}

// ------------------- CSR build -------------------
__global__ void k_count(const int* __restrict__ col, int* __restrict__ deg, int E) {
    int e = blockIdx.x * blockDim.x + threadIdx.x;
    if (e < E) atomicAdd(&deg[col[e]], 1);
}

// multi-block scan, phase 1: per-block sums (1024 elems/block)
__global__ __launch_bounds__(256) void k_bsum(const int* __restrict__ deg,
                                              int* __restrict__ bsum, int N) {
    int base = blockIdx.x * 1024 + threadIdx.x * 4;
    int s = 0;
    if (base + 3 < N) {
        int4 v = *(const int4*)(deg + base);
        s = v.x + v.y + v.z + v.w;
    } else {
        for (int j = 0; j < 4; j++) if (base + j < N) s += deg[base + j];
    }
    __shared__ int red[256];
    red[threadIdx.x] = s;
    __syncthreads();
    for (int off = 128; off > 0; off >>= 1) {
        if (threadIdx.x < off) red[threadIdx.x] += red[threadIdx.x + off];
        __syncthreads();
    }
    if (threadIdx.x == 0) bsum[blockIdx.x] = red[0];
}

// phase 2: scan the (<=128) block sums -> exclusive offsets
__global__ __launch_bounds__(128) void k_scanb(const int* __restrict__ bsum,
                                               int* __restrict__ boff, int NB) {
    __shared__ int sh[128];
    int t = threadIdx.x;
    int v = (t < NB) ? bsum[t] : 0;
    sh[t] = v;
    __syncthreads();
    for (int off = 1; off < 128; off <<= 1) {
        int add = (t >= off) ? sh[t - off] : 0;
        __syncthreads();
        sh[t] += add;
        __syncthreads();
    }
    if (t < NB) boff[t] = sh[t] - v;
}

// phase 3: block-local scan + offset -> indptr
__global__ __launch_bounds__(256) void k_indptr(const int* __restrict__ deg,
                                                const int* __restrict__ boff,
                                                int* __restrict__ indptr, int N) {
    int b = blockIdx.x, t = threadIdx.x;
    int base = b * 1024 + t * 4;
    int v[4] = {0, 0, 0, 0};
    if (base + 3 < N) {
        int4 w = *(const int4*)(deg + base);
        v[0] = w.x; v[1] = w.y; v[2] = w.z; v[3] = w.w;
    } else {
        for (int j = 0; j < 4; j++) if (base + j < N) v[j] = deg[base + j];
    }
    int tsum = v[0] + v[1] + v[2] + v[3];
    __shared__ int sh[256];
    sh[t] = tsum;
    __syncthreads();
    for (int off = 1; off < 256; off <<= 1) {
        int add = (t >= off) ? sh[t - off] : 0;
        __syncthreads();
        sh[t] += add;
        __syncthreads();
    }
    int run = boff[b] + sh[t] - tsum;
    for (int j = 0; j < 4; j++) {
        run += v[j];
        if (base + j < N) indptr[base + j + 1] = run;
    }
    if (b == 0 && t == 0) indptr[0] = 0;
}

__global__ void k_fill(const int* __restrict__ row, const int* __restrict__ col,
                       const int* __restrict__ et, const int* __restrict__ ed,
                       const int* __restrict__ indptr, int* __restrict__ cursor,
                       int* __restrict__ packed, int E) {
    int e = blockIdx.x * blockDim.x + threadIdx.x;
    if (e >= E) return;
    int c = col[e];
    int pos = indptr[c] + atomicAdd(&cursor[c], 1);
    packed[pos] = row[e] | ((et[e] * 3 + ed[e]) << 17);
}

// ------------------- comb table: comb[at*3+ch] = bf16(e1[at] + e2[ch]) --------
__global__ void k_comb(const float* __restrict__ e1, const float* __restrict__ e2,
                       u16* __restrict__ comb) {
    int idx = blockIdx.x * blockDim.x + threadIdx.x;
    if (idx >= NCOMB * 40) return;
    int row = idx / 40, f = idx % 40;
    int at = row / 3, ch = row % 3;
    u32 o[4];
#pragma unroll
    for (int q = 0; q < 4; q++) {
        int c0 = f * 8 + q * 2;
        float x0 = 0.f, x1 = 0.f;
        if (c0 < EMB)     x0 = e1[(size_t)at * EMB + c0] + e2[(size_t)ch * EMB + c0];
        if (c0 + 1 < EMB) x1 = e1[(size_t)at * EMB + c0 + 1] + e2[(size_t)ch * EMB + c0 + 1];
        o[q] = (u32)f2bf(x0) | ((u32)f2bf(x1) << 16);
    }
    *(uint4*)(comb + (size_t)row * SP + f * 8) = make_uint4(o[0], o[1], o[2], o[3]);
}

__global__ void k_c9(const int* __restrict__ at, const int* __restrict__ ch,
                     int* __restrict__ c9, int N) {
    int n = blockIdx.x * blockDim.x + threadIdx.x;
    if (n < N) c9[n] = at[n] * 3 + ch[n];
}

// ------------------- W -> bf16 transposed, padded [SP x SP] -------------------
__global__ void k_wconv(const float* __restrict__ Wl, u16* __restrict__ Wt) {
    int idx = blockIdx.x * blockDim.x + threadIdx.x;
    if (idx >= SP * SP) return;
    int n = idx / SP, k = idx % SP;
    float v = (n < EMB && k < EMB) ? Wl[k * EMB + n] : 0.f;
    Wt[idx] = f2bf(v);  // Wt[n*SP + k] = W[k][n]
}

// ------------------- identity / BN-finalize scale+shift -------------------
__global__ void k_ident(float* __restrict__ sc, float* __restrict__ sh) {
    int c = threadIdx.x;
    if (c < SP) { sc[c] = (c < EMB) ? 1.f : 0.f; sh[c] = 0.f; }
}

__global__ void k_finalize(const float* __restrict__ colsum, const float* __restrict__ colsq,
                           const float* __restrict__ gamma, const float* __restrict__ beta,
                           float* __restrict__ sc, float* __restrict__ sh, int N) {
    int c = threadIdx.x;
    if (c >= SP) return;
    if (c < EMB) {
        float inv = 1.f / (float)N;
        float mean = colsum[c] * inv;
        float var = colsq[c] * inv - mean * mean;
        float rstd = rsqrtf(fmaxf(var, 0.f) + 1e-5f);
        float s = gamma[c] * rstd;
        sc[c] = s;
        sh[c] = beta[c] - mean * s;
    } else {
        sc[c] = 0.f; sh[c] = 0.f;
    }
}

// ------------------- GEMM: Q = BNrelu(A[rowmap]) @ W[l]  (bf16 in/out) -------
// A: [*, SP] bf16; Wt: [SP, SP] bf16 (Wt[n][k] = W[k][n]); C: [M, SP] bf16
// block tile 128m x 160n, 4 waves 2x2, wave tile 64x80
__global__ __launch_bounds__(256) void k_gemm(
    const u16* __restrict__ A, const u16* __restrict__ Wt,
    const float* __restrict__ scale, const float* __restrict__ shift,
    int relu, u16* __restrict__ C, int M, const int* __restrict__ rowmap) {
    __shared__ __align__(16) char smem[43008];
    u16* As = (u16*)smem;               // [128][40]
    u16* Bs = (u16*)(smem + 10240);     // [160][40]
    u16* Ct = (u16*)smem;               // [128][168] (overlays staging)

    int m0 = blockIdx.y * MT;
    int n0 = blockIdx.x * NT;
    int tid = threadIdx.x;
    int wave = tid >> 6, lane = tid & 63;
    int wm = wave >> 1, wn = wave & 1;
    int lm = lane & 15, quad = lane >> 4;

    v4f acc[4][5] = {};

    for (int kt = 0; kt < SP / 32; ++kt) {
        int k0 = kt * 32;
        // stage A: 128 rows x 32 cols, bf16 -> BN+relu -> bf16 (512 slots)
#pragma unroll
        for (int i = 0; i < 2; i++) {
            int slot = tid + i * 256;
            int r = slot >> 2, f = slot & 3;
            int m = m0 + r;
            int c = k0 + f * 8;
            uint4 w = make_uint4(0, 0, 0, 0);
            if (m < M) {
                int msrc = rowmap ? rowmap[m] : m;
                w = *(const uint4*)(A + (size_t)msrc * SP + c);
            }
            const u32* wp = &w.x;
            u32 o[4];
#pragma unroll
            for (int q = 0; q < 4; q++) {
                float x0 = __uint_as_float(wp[q] << 16);
                float x1 = __uint_as_float(wp[q] & 0xFFFF0000u);
                x0 = x0 * scale[c + q * 2]     + shift[c + q * 2];
                x1 = x1 * scale[c + q * 2 + 1] + shift[c + q * 2 + 1];
                if (relu) { x0 = fmaxf(x0, 0.f); x1 = fmaxf(x1, 0.f); }
                o[q] = (u32)f2bf(x0) | ((u32)f2bf(x1) << 16);
            }
            *(uint4*)(As + r * 40 + f * 8) = make_uint4(o[0], o[1], o[2], o[3]);
        }
        // stage B: 160 rows (n) x 32 cols (k) (640 slots)
        for (int slot = tid; slot < 640; slot += 256) {
            int r = slot >> 2, f = slot & 3;
            *(uint4*)(Bs + r * 40 + f * 8) =
                *(const uint4*)(Wt + (size_t)(n0 + r) * SP + k0 + f * 8);
        }
        __syncthreads();
        v8s a[4];
#pragma unroll
        for (int mf = 0; mf < 4; mf++)
            a[mf] = *(const v8s*)(As + (wm * 64 + mf * 16 + lm) * 40 + quad * 8);
#pragma unroll
        for (int nf = 0; nf < 5; nf++) {
            v8s b = *(const v8s*)(Bs + (wn * 80 + nf * 16 + lm) * 40 + quad * 8);
#pragma unroll
            for (int mf = 0; mf < 4; mf++)
                acc[mf][nf] = __builtin_amdgcn_mfma_f32_16x16x32_bf16(a[mf], b, acc[mf][nf], 0, 0, 0);
        }
        __syncthreads();
    }
    // epilogue: acc -> LDS (bf16) -> coalesced global stores
#pragma unroll
    for (int mf = 0; mf < 4; mf++)
#pragma unroll
        for (int nf = 0; nf < 5; nf++)
#pragma unroll
            for (int r = 0; r < 4; r++) {
                int row = wm * 64 + mf * 16 + quad * 4 + r;
                int col = wn * 80 + nf * 16 + lm;
                Ct[row * 168 + col] = f2bf(acc[mf][nf][r]);
            }
    __syncthreads();
#pragma unroll
    for (int i = 0; i < 10; i++) {
        int slot = tid + i * 256;
        int r = slot / 20, c16 = slot % 20;
        if (m0 + r < M)
            *(uint4*)(C + (size_t)(m0 + r) * SP + n0 + c16 * 8) =
                *(const uint4*)(Ct + r * 168 + c16 * 8);
    }
}

// ------------------- aggregate + fused BN stats -------------------
// P[n] = Q[n] + sum_in Q[src] + S[n];  colstats += column sums/sqsums of P
__global__ __launch_bounds__(320) void k_agg(
    const u16* __restrict__ Q, const int* __restrict__ indptr,
    const int* __restrict__ packed, const float* __restrict__ e1,
    const float* __restrict__ e2, u16* __restrict__ P,
    float* __restrict__ colstats, int N) {
    __shared__ float tab[12];
    __shared__ float part[8][328];
    int tid = threadIdx.x;
    if (tid < 12) tab[tid] = e1[tid / 3] + e2[tid % 3];
    __syncthreads();
    int f = tid % 40;
    int slot = tid / 40;
    int nb = blockIdx.x * 64;
    float sbase = e1[4] + e2[0];   // self loop: et=4, ed=0
    float psum[8] = {0, 0, 0, 0, 0, 0, 0, 0};
    float psq[8]  = {0, 0, 0, 0, 0, 0, 0, 0};

    for (int it = 0; it < 8; it++) {
        int n = nb + it * 8 + slot;
        if (n >= N) continue;
        float acc[8];
        unpack8(*(const uint4*)(Q + (size_t)n * SP + f * 8), acc);
        float s = sbase;
        int beg = indptr[n], end = indptr[n + 1];
        for (int i = beg; i < end; i++) {
            int v = packed[i];
            int src = v & 0x1FFFF;
            float t[8];
            unpack8(*(const uint4*)(Q + (size_t)src * SP + f * 8), t);
#pragma unroll
            for (int j = 0; j < 8; j++) acc[j] += t[j];
            s += tab[v >> 17];
        }
        u32 o[4];
#pragma unroll
        for (int q = 0; q < 4; q++) {
            float r0 = acc[q * 2] + s;
            float r1 = acc[q * 2 + 1] + s;
            psum[q * 2] += r0;       psum[q * 2 + 1] += r1;
            psq[q * 2]  += r0 * r0;  psq[q * 2 + 1]  += r1 * r1;
            o[q] = (u32)f2bf(r0) | ((u32)f2bf(r1) << 16);
        }
        *(uint4*)(P + (size_t)n * SP + f * 8) = make_uint4(o[0], o[1], o[2], o[3]);
    }
    // reduce partials over the 8 node-slots, two rounds (sum then sq)
#pragma unroll
    for (int j = 0; j < 8; j++) part[slot][f * 8 + j] = psum[j];
    __syncthreads();
    {
        float s = 0.f;
#pragma unroll
        for (int k = 0; k < 8; k++) s += part[k][tid];
        atomicAdd(&colstats[tid], s);
    }
    __syncthreads();
#pragma unroll
    for (int j = 0; j < 8; j++) part[slot][f * 8 + j] = psq[j];
    __syncthreads();
    {
        float s = 0.f;
#pragma unroll
        for (int k = 0; k < 8; k++) s += part[k][tid];
        atomicAdd(&colstats[SP + tid], s);
    }
}

// ------------------- group boundaries from sorted batch -------------------
__global__ void k_bounds(const int* __restrict__ batch, int* __restrict__ gstart, int N) {
    int n = blockIdx.x * blockDim.x + threadIdx.x;
    if (n > N) return;
    int bcur = (n < N) ? batch[n] : NGRP;
    int bprev = (n > 0) ? batch[n - 1] : -1;
    for (int g = bprev + 1; g <= bcur; g++) gstart[g] = n;
}

// ------------------- pool (BN layer4 fused, no relu), 8 groups/block ----------
__global__ __launch_bounds__(320) void k_pool(
    const u16* __restrict__ P, const float* __restrict__ sc,
    const float* __restrict__ sh, const int* __restrict__ gstart,
    float* __restrict__ hg) {
    int tid = threadIdx.x;
    int g = blockIdx.x * 8 + tid / 40;
    int f = tid % 40;
    int r0 = gstart[g], r1 = gstart[g + 1];
    int cnt = r1 - r0;
    float acc[8] = {0, 0, 0, 0, 0, 0, 0, 0};
    for (int r = r0; r < r1; r++) {
        float t[8];
        unpack8(*(const uint4*)(P + (size_t)r * SP + f * 8), t);
#pragma unroll
        for (int j = 0; j < 8; j++) acc[j] += t[j];
    }
    float inv = 1.f / (float)max(cnt, 1);
#pragma unroll
    for (int j = 0; j < 8; j++) {
        int c = f * 8 + j;
        if (c < EMB)
            hg[(size_t)g * EMB + c] = (acc[j] * sc[c] + (float)cnt * sh[c]) * inv;
    }
}

// ------------------- hf = hg @ feat_W + feat_b -------------------
__global__ __launch_bounds__(256) void k_feat(const float* __restrict__ hg,
                                              const float* __restrict__ fW,
                                              const float* __restrict__ fb,
                                              float* __restrict__ hf) {
    __shared__ float hgs[16 * EMB];
    int g0 = blockIdx.x * 16;
    int tid = threadIdx.x;
    for (int i = tid; i < 16 * EMB; i += 256) {
        int gi = i / EMB, c = i % EMB;
        hgs[i] = hg[(size_t)(g0 + gi) * EMB + c];
    }
    __syncthreads();
    float acc[16];
    float fbv = fb[tid];
#pragma unroll
    for (int gi = 0; gi < 16; gi++) acc[gi] = fbv;
    for (int k = 0; k < EMB; k++) {
        float w = fW[(size_t)k * FEAT + tid];
#pragma unroll
        for (int gi = 0; gi < 16; gi++) acc[gi] += hgs[gi * EMB + k] * w;
    }
#pragma unroll
    for (int gi = 0; gi < 16; gi++) hf[(size_t)(g0 + gi) * FEAT + tid] = acc[gi];
}

// ------------------- head: pred = softplus(hf@W1+b1)@W2+b2 -------------------
__global__ __launch_bounds__(128) void k_head(const float* __restrict__ hf,
                                              const float* __restrict__ W1,
                                              const float* __restrict__ b1,
                                              const float* __restrict__ W2,
                                              const float* __restrict__ b2,
                                              float* __restrict__ pred) {
    __shared__ float hfs[8 * FEAT];
    __shared__ float sred[2][8][2];
    int g0 = blockIdx.x * 8;
    int tid = threadIdx.x;
    for (int i = tid; i < 8 * FEAT; i += 128) {
        int gi = i >> 8, k = i & 255;
        hfs[i] = hf[(size_t)(g0 + gi) * FEAT + k];
    }
    __syncthreads();
    float acc[8];
    float b1v = b1[tid];
#pragma unroll
    for (int gi = 0; gi < 8; gi++) acc[gi] = b1v;
    for (int k = 0; k < FEAT; k++) {
        float w = W1[(size_t)k * 128 + tid];
#pragma unroll
        for (int gi = 0; gi < 8; gi++) acc[gi] += hfs[gi * FEAT + k] * w;
    }
    float w20 = W2[tid * 2], w21 = W2[tid * 2 + 1];
    int wv = tid >> 6;
#pragma unroll
    for (int gi = 0; gi < 8; gi++) {
        float x = acc[gi];
        float t = fmaxf(x, 0.f) + log1pf(expf(-fabsf(x)));
        float p0 = t * w20, p1 = t * w21;
#pragma unroll
        for (int off = 32; off > 0; off >>= 1) {
            p0 += __shfl_down(p0, off);
            p1 += __shfl_down(p1, off);
        }
        if ((tid & 63) == 0) { sred[wv][gi][0] = p0; sred[wv][gi][1] = p1; }
    }
    __syncthreads();
    if (tid < 16) {
        int gi = tid >> 1, o = tid & 1;
        pred[(size_t)(g0 + gi) * 2 + o] = sred[0][gi][o] + sred[1][gi][o] + b2[o];
    }
}

// ------------------- launch -------------------
extern "C" void kernel_launch(void* const* d_in, const int* in_sizes, int n_in,
                              void* d_out, int out_size, void* d_ws, size_t ws_size,
                              hipStream_t stream) {
    const int* atom_type = (const int*)d_in[0];
    const int* chir      = (const int*)d_in[1];
    const int* eidx      = (const int*)d_in[2];
    const int* etype     = (const int*)d_in[3];
    const int* edir      = (const int*)d_in[4];
    const int* batch     = (const int*)d_in[5];
    const float* emb1    = (const float*)d_in[6];
    const float* emb2    = (const float*)d_in[7];
    const float* W       = (const float*)d_in[8];
    const float* ee1     = (const float*)d_in[10];
    const float* ee2     = (const float*)d_in[11];
    const float* gamma   = (const float*)d_in[12];
    const float* beta    = (const float*)d_in[13];
    const float* featW   = (const float*)d_in[14];
    const float* featb   = (const float*)d_in[15];
    const float* hW1     = (const float*)d_in[16];
    const float* hb1     = (const float*)d_in[17];
    const float* hW2     = (const float*)d_in[18];
    const float* hb2     = (const float*)d_in[19];

    int N = in_sizes[0];
    int E = in_sizes[2] / 2;
    const int* erow = eidx;
    const int* ecol = eidx + E;

    size_t off = 0;
    char* base = (char*)d_ws;
    auto carve = [&](size_t bytes) -> void* {
        void* p = base + off;
        off += (bytes + 255) & ~(size_t)255;
        return p;
    };
    u16*   P        = (u16*)  carve((size_t)N * SP * 2);
    u16*   Q        = (u16*)  carve((size_t)N * SP * 2);
    u16*   Wt       = (u16*)  carve((size_t)SP * SP * 2);
    u16*   comb     = (u16*)  carve((size_t)NCOMB * SP * 2);
    int*   c9map    = (int*)  carve((size_t)N * 4);
    int*   deg      = (int*)  carve((size_t)N * 4);
    int*   cursor   = (int*)  carve((size_t)N * 4);
    int*   indptr   = (int*)  carve((size_t)(N + 1) * 4);
    int*   packed   = (int*)  carve((size_t)E * 4);
    int*   bsum     = (int*)  carve(1024 * 4);
    int*   boff     = (int*)  carve(1024 * 4);
    float* colstats = (float*)carve(2 * SP * 4);
    float* scale_id = (float*)carve(SP * 4);
    float* shift_id = (float*)carve(SP * 4);
    float* scale_bn = (float*)carve(SP * 4);
    float* shift_bn = (float*)carve(SP * 4);
    int*   gstart   = (int*)  carve((size_t)(NGRP + 1) * 4);
    float* hg       = (float*)carve((size_t)NGRP * EMB * 4);

    float* hf   = (float*)d_out;
    float* pred = (float*)d_out + (size_t)NGRP * FEAT;

    hipMemsetAsync(deg, 0, (size_t)N * 4, stream);
    hipMemsetAsync(cursor, 0, (size_t)N * 4, stream);

    int eb = (E + 255) / 256;
    int NB = (N + 1023) / 1024;
    k_count<<<eb, 256, 0, stream>>>(ecol, deg, E);
    k_bsum<<<NB, 256, 0, stream>>>(deg, bsum, N);
    k_scanb<<<1, 128, 0, stream>>>(bsum, boff, NB);
    k_indptr<<<NB, 256, 0, stream>>>(deg, boff, indptr, N);
    k_fill<<<eb, 256, 0, stream>>>(erow, ecol, etype, edir, indptr, cursor, packed, E);

    k_comb<<<(NCOMB * 40 + 255) / 256, 256, 0, stream>>>(emb1, emb2, comb);
    k_c9<<<(N + 255) / 256, 256, 0, stream>>>(atom_type, chir, c9map, N);
    k_ident<<<1, SP, 0, stream>>>(scale_id, shift_id);

    const float* sc = scale_id;
    const float* sh = shift_id;
    dim3 ggrid(2, (N + MT - 1) / MT);   // x = n-tile (fast), y = m-tile
    int ab = (N + 63) / 64;
    for (int l = 0; l < 5; l++) {
        k_wconv<<<(SP * SP + 255) / 256, 256, 0, stream>>>(W + (size_t)l * EMB * EMB, Wt);
        if (l == 0)
            k_gemm<<<ggrid, 256, 0, stream>>>(comb, Wt, sc, sh, 0, Q, N, c9map);
        else
            k_gemm<<<ggrid, 256, 0, stream>>>(P, Wt, sc, sh, 1, Q, N, nullptr);
        hipMemsetAsync(colstats, 0, 2 * SP * 4, stream);
        k_agg<<<ab, 320, 0, stream>>>(Q, indptr, packed, ee1 + l * 5, ee2 + l * 3, P,
                                      colstats, N);
        k_finalize<<<1, SP, 0, stream>>>(colstats, colstats + SP, gamma + l * EMB,
                                         beta + l * EMB, scale_bn, shift_bn, N);
        sc = scale_bn; sh = shift_bn;
    }

    k_bounds<<<(N + 1 + 255) / 256, 256, 0, stream>>>(batch, gstart, N);
    k_pool<<<NGRP / 8, 320, 0, stream>>>(P, scale_bn, shift_bn, gstart, hg);
    k_feat<<<NGRP / 16, 256, 0, stream>>>(hg, featW, featb, hf);
    k_head<<<NGRP / 8, 128, 0, stream>>>(hf, hW1, hb1, hW2, hb2, pred);
}